// Round 1
// baseline (164.813 us; speedup 1.0000x reference)
//
#include <hip/hip_runtime.h>

typedef _Float16 f16x8 __attribute__((ext_vector_type(8)));
typedef _Float16 f16x4 __attribute__((ext_vector_type(4)));
typedef float f32x4 __attribute__((ext_vector_type(4)));

#define B_  8
#define LQ  2048
#define LC  4096
#define DD  256

// async global->LDS, 16B per lane. LDS dest must be wave-uniform-base + lane*16.
__device__ __forceinline__ void gload_lds16(const void* g, void* l) {
    __builtin_amdgcn_global_load_lds(
        (const __attribute__((address_space(1))) unsigned int*)g,
        (__attribute__((address_space(3))) unsigned int*)l,
        16, 0, 0);
}

__global__ __launch_bounds__(256)
void convert_f32_f16(const float* __restrict__ in, _Float16* __restrict__ out, int n) {
    const int i = (blockIdx.x * blockDim.x + threadIdx.x) * 4;
    if (i < n) {
        const float4 v = *(const float4*)(in + i);
        f16x4 o;
        o[0] = (_Float16)v.x;
        o[1] = (_Float16)v.y;
        o[2] = (_Float16)v.z;
        o[3] = (_Float16)v.w;
        *(f16x4*)(out + i) = o;
    }
}

// Computes, per (b, mt, nt): the 128x128 S tile (context rows x query cols),
// K=256 in 4 chunks of 64, f16 MFMA 16x16x32; epilogue reduces max over the
// 128 query cols and writes partial max sp[b][nt][c].
__global__ __launch_bounds__(256, 2)
void gemm_max_kernel(const _Float16* __restrict__ qf,
                     const _Float16* __restrict__ cf,
                     float* __restrict__ sp) {
    __shared__ __align__(16) _Float16 As[128 * 64];   // context tile, row-major, 64 halfs/row
    __shared__ __align__(16) _Float16 Bs[128 * 64];   // query tile
    __shared__ float red[2][128];

    const int nt = blockIdx.x;   // query tile   0..15
    const int mt = blockIdx.y;   // context tile 0..31
    const int b  = blockIdx.z;   // batch        0..7

    const int tid  = threadIdx.x;
    const int lane = tid & 63;
    const int wave = tid >> 6;
    const int wm   = wave >> 1;  // 0..1 row half
    const int wn   = wave & 1;   // 0..1 col half
    const int quad = lane >> 4;
    const int l15  = lane & 15;

    const _Float16* Ag = cf + ((size_t)b * LC + (size_t)mt * 128) * DD;
    const _Float16* Bg = qf + ((size_t)b * LQ + (size_t)nt * 128) * DD;

    const int srow = tid >> 3;        // staging row within 32-row pass
    const int scol = (tid & 7) * 8;   // staging col (half index) within 64

    f32x4 acc[4][4];
#pragma unroll
    for (int mi = 0; mi < 4; ++mi)
#pragma unroll
        for (int ni = 0; ni < 4; ++ni)
            acc[mi][ni] = (f32x4)0.0f;

#pragma unroll
    for (int kc = 0; kc < 4; ++kc) {
        __syncthreads();
        const int kb = kc * 64 + scol;
#pragma unroll
        for (int p = 0; p < 4; ++p) {
            const int row = p * 32 + srow;
            gload_lds16(Ag + (size_t)row * DD + kb, (char*)As + p * 4096 + tid * 16);
            gload_lds16(Bg + (size_t)row * DD + kb, (char*)Bs + p * 4096 + tid * 16);
        }
        __syncthreads();   // compiler emits vmcnt(0) drain here -> LDS valid
#pragma unroll
        for (int ks = 0; ks < 2; ++ks) {
            const int kh = ks * 32 + quad * 8;
            f16x8 af[4], bf[4];
#pragma unroll
            for (int mi = 0; mi < 4; ++mi)
                af[mi] = *(const f16x8*)&As[(wm * 64 + mi * 16 + l15) * 64 + kh];
#pragma unroll
            for (int ni = 0; ni < 4; ++ni)
                bf[ni] = *(const f16x8*)&Bs[(wn * 64 + ni * 16 + l15) * 64 + kh];
#pragma unroll
            for (int mi = 0; mi < 4; ++mi)
#pragma unroll
                for (int ni = 0; ni < 4; ++ni)
                    acc[mi][ni] = __builtin_amdgcn_mfma_f32_16x16x32_f16(
                        af[mi], bf[ni], acc[mi][ni], 0, 0, 0);
        }
    }

    // C/D layout: col(query) = lane&15, row(context) = quad*4 + reg.
    // Max over this wave's 64 query cols: over ni then over the 16 col-lanes.
    float rmax[4][4];
#pragma unroll
    for (int mi = 0; mi < 4; ++mi)
#pragma unroll
        for (int r = 0; r < 4; ++r) {
            float v = fmaxf(fmaxf(acc[mi][0][r], acc[mi][1][r]),
                            fmaxf(acc[mi][2][r], acc[mi][3][r]));
            rmax[mi][r] = v;
        }
#pragma unroll
    for (int sh = 1; sh <= 8; sh <<= 1)
#pragma unroll
        for (int mi = 0; mi < 4; ++mi)
#pragma unroll
            for (int r = 0; r < 4; ++r)
                rmax[mi][r] = fmaxf(rmax[mi][r], __shfl_xor(rmax[mi][r], sh, 64));

    if (l15 == 0) {
#pragma unroll
        for (int mi = 0; mi < 4; ++mi)
#pragma unroll
            for (int r = 0; r < 4; ++r)
                red[wn][wm * 64 + mi * 16 + quad * 4 + r] = rmax[mi][r];
    }
    __syncthreads();
    if (tid < 128) {
        const float s = fmaxf(red[0][tid], red[1][tid]);
        sp[((size_t)b * 16 + nt) * LC + mt * 128 + tid] = s;
    }
}

// Per batch: reduce 16 partial maxes, softmax over 4096 contexts, write probs.
__global__ __launch_bounds__(256)
void stats_kernel(const float* __restrict__ sp, float* __restrict__ probs) {
    const int b    = blockIdx.x;
    const int tid  = threadIdx.x;
    const int lane = tid & 63;
    const int wave = tid >> 6;
    __shared__ float smax[4];
    __shared__ float ssum[4];

    float sv[16];
    float lmax = -3.4e38f;
#pragma unroll
    for (int j = 0; j < 16; ++j) {
        const int c = tid + j * 256;
        float v = -3.4e38f;
#pragma unroll
        for (int ntt = 0; ntt < 16; ++ntt)
            v = fmaxf(v, sp[((size_t)b * 16 + ntt) * LC + c]);
        sv[j] = v;
        lmax  = fmaxf(lmax, v);
    }
    for (int sh = 1; sh < 64; sh <<= 1)
        lmax = fmaxf(lmax, __shfl_xor(lmax, sh, 64));
    if (lane == 0) smax[wave] = lmax;
    __syncthreads();
    const float M = fmaxf(fmaxf(smax[0], smax[1]), fmaxf(smax[2], smax[3]));

    float lsum = 0.f;
#pragma unroll
    for (int j = 0; j < 16; ++j) {
        sv[j] = expf(sv[j] - M);
        lsum += sv[j];
    }
    for (int sh = 1; sh < 64; sh <<= 1)
        lsum += __shfl_xor(lsum, sh, 64);
    if (lane == 0) ssum[wave] = lsum;
    __syncthreads();
    const float inv = 1.f / (ssum[0] + ssum[1] + ssum[2] + ssum[3]);
#pragma unroll
    for (int j = 0; j < 16; ++j)
        probs[(size_t)b * LC + tid + j * 256] = sv[j] * inv;
}

// out[b][d] = sum_c probs[b][c] * ctx[b][c][d]; 32 c-chunks/batch + atomicAdd.
__global__ __launch_bounds__(256)
void out_kernel(const float* __restrict__ probs, const float* __restrict__ ctx,
                float* __restrict__ out) {
    const int ch = blockIdx.x;   // 0..31
    const int b  = blockIdx.y;   // 0..7
    const int d  = threadIdx.x;  // 0..255
    const float* cb = ctx + (((size_t)b * LC) + (size_t)ch * 128) * DD;
    const float* pb = probs + (size_t)b * LC + ch * 128;
    float acc = 0.f;
#pragma unroll 4
    for (int i = 0; i < 128; ++i)
        acc += pb[i] * cb[(size_t)i * DD + d];
    atomicAdd(&out[b * DD + d], acc);
}

extern "C" void kernel_launch(void* const* d_in, const int* in_sizes, int n_in,
                              void* d_out, int out_size, void* d_ws, size_t ws_size,
                              hipStream_t stream) {
    const float* q   = (const float*)d_in[0];   // [8, 2048, 256] f32
    const float* ctx = (const float*)d_in[1];   // [8, 4096, 256] f32
    float* out = (float*)d_out;                 // [8, 1, 256] f32

    // ws layout (bytes):
    //   qf    @ 0         : 8*2048*256*2  =  8,388,608
    //   cf    @ 8388608   : 8*4096*256*2  = 16,777,216
    //   sp    @ 25165824  : 8*16*4096*4   =  2,097,152   (partial maxes)
    //   probs @ 27262976  : 8*4096*4      =    131,072
    // total ~27.4 MB
    char* ws = (char*)d_ws;
    _Float16* qf = (_Float16*)(ws);
    _Float16* cf = (_Float16*)(ws + 8388608);
    float* sp    = (float*)(ws + 25165824);
    float* probs = (float*)(ws + 27262976);

    hipMemsetAsync(d_out, 0, (size_t)out_size * sizeof(float), stream);
    convert_f32_f16<<<4096, 256, 0, stream>>>(q,   qf, B_ * LQ * DD);
    convert_f32_f16<<<8192, 256, 0, stream>>>(ctx, cf, B_ * LC * DD);
    gemm_max_kernel<<<dim3(16, 32, 8), 256, 0, stream>>>(qf, cf, sp);
    stats_kernel<<<8, 256, 0, stream>>>(sp, probs);
    out_kernel<<<dim3(32, 8), 256, 0, stream>>>(probs, ctx, out);
}

// Round 2
// 137.943 us; speedup vs baseline: 1.1948x; 1.1948x over previous
//
#include <hip/hip_runtime.h>

typedef _Float16 f16x8 __attribute__((ext_vector_type(8)));
typedef _Float16 f16x4 __attribute__((ext_vector_type(4)));
typedef float f32x4 __attribute__((ext_vector_type(4)));

#define B_  8
#define LQ  2048
#define LC  4096
#define DD  256

// async global->LDS, 16B per lane. LDS dest is wave-uniform base + lane*16.
__device__ __forceinline__ void gload_lds16(const void* g, void* l) {
    __builtin_amdgcn_global_load_lds(
        (const __attribute__((address_space(1))) unsigned int*)g,
        (__attribute__((address_space(3))) unsigned int*)l,
        16, 0, 0);
}

// Fused f32->f16 convert of query then context (one launch).
__global__ __launch_bounds__(256)
void convert_all(const float* __restrict__ q, const float* __restrict__ c,
                 _Float16* __restrict__ qf, _Float16* __restrict__ cf) {
    const int NQ = B_ * LQ * DD;                       // 4,194,304 (divisible by 1024)
    const int i = (blockIdx.x * 256 + threadIdx.x) * 4;
    if (i < NQ) {
        const float4 v = *(const float4*)(q + i);
        f16x4 o;
        o[0] = (_Float16)v.x; o[1] = (_Float16)v.y;
        o[2] = (_Float16)v.z; o[3] = (_Float16)v.w;
        *(f16x4*)(qf + i) = o;
    } else {
        const int j = i - NQ;
        const float4 v = *(const float4*)(c + j);
        f16x4 o;
        o[0] = (_Float16)v.x; o[1] = (_Float16)v.y;
        o[2] = (_Float16)v.z; o[3] = (_Float16)v.w;
        *(f16x4*)(cf + j) = o;
    }
}

// One block per (b, 128-context tile). A (context) fragments resident in VGPRs
// for full K=256; B (query) chunks 128x64 double-buffered via global_load_lds.
// XOR swizzle: 16B group g of row r is stored at position g^(r&7) -> frag
// ds_read_b128 spreads over all 32 banks (2-way = free).
// Writes FINAL scores[b][c] = max over all 2048 queries.
__global__ __launch_bounds__(256, 1)
void gemm_max_kernel(const _Float16* __restrict__ qf,
                     const _Float16* __restrict__ cf,
                     float* __restrict__ scores) {
    __shared__ __align__(16) _Float16 Buf[2][128 * 64];   // 2 x 16 KB
    __shared__ float red[2][128];

    const int mt = blockIdx.x;   // context tile 0..31
    const int b  = blockIdx.y;   // batch 0..7

    const int tid  = threadIdx.x;
    const int lane = tid & 63;
    const int wave = tid >> 6;
    const int wm   = wave >> 1;  // ctx half
    const int wn   = wave & 1;   // query half
    const int quad = lane >> 4;
    const int l15  = lane & 15;

    const _Float16* Ag = cf + ((size_t)b * LC + (size_t)mt * 128) * DD;
    const _Float16* Bg = qf + (size_t)b * LQ * DD;

    // staging: thread t -> row srow (per 32-row pass), stores LDS group g_store,
    // fetches global group g_glob = g_store ^ (row&7).
    const int srow    = tid >> 3;
    const int g_store = tid & 7;
    const int g_glob  = g_store ^ (srow & 7);

    // src = tile base + kc*64 (row stride DD)
    #define STAGE(src, bufi)                                                     \
        {                                                                        \
            const _Float16* _s = (src);                                          \
            _Pragma("unroll")                                                    \
            for (int p = 0; p < 4; ++p)                                          \
                gload_lds16(_s + ((size_t)(p * 32 + srow)) * DD + g_glob * 8,    \
                            (char*)Buf[bufi] + p * 4096 + tid * 16);             \
        }

    // ---- prologue: A fragments -> registers (4 chunks through the B buffers)
    f16x8 af[4][8];   // [mi][ks 0..7], k = ks*32 + quad*8 .. +8
    STAGE(Ag, 0);
#pragma unroll
    for (int kc = 0; kc < 4; ++kc) {
        __syncthreads();                          // chunk kc landed
        if (kc < 3) STAGE(Ag + (kc + 1) * 64, (kc + 1) & 1);
#pragma unroll
        for (int ksl = 0; ksl < 2; ++ksl) {
#pragma unroll
            for (int mi = 0; mi < 4; ++mi) {
                const int row = wm * 64 + mi * 16 + l15;
                const int pos = (ksl * 4 + quad) ^ (row & 7);
                af[mi][kc * 2 + ksl] =
                    *(const f16x8*)((const char*)Buf[kc & 1] + row * 128 + pos * 16);
            }
        }
    }

    float rm[4][4];
#pragma unroll
    for (int mi = 0; mi < 4; ++mi)
#pragma unroll
        for (int r = 0; r < 4; ++r)
            rm[mi][r] = -3.4e38f;

    __syncthreads();            // all A-frag reads done; buffers free
    STAGE(Bg, 0);               // B chunk (nt=0, kc=0) -> buf 0

    // ---- main loop: 16 query tiles x 4 K-chunks, issue-after-barrier dbuf
#pragma unroll 1
    for (int nt = 0; nt < 16; ++nt) {
        f32x4 acc[4][4];
#pragma unroll
        for (int mi = 0; mi < 4; ++mi)
#pragma unroll
            for (int ni = 0; ni < 4; ++ni)
                acc[mi][ni] = (f32x4)0.0f;

#pragma unroll
        for (int kc = 0; kc < 4; ++kc) {
            const int i = nt * 4 + kc;
            __syncthreads();                      // chunk i landed in Buf[i&1]
            if (kc < 3)
                STAGE(Bg + (size_t)nt * 128 * DD + (kc + 1) * 64, (i + 1) & 1)
            else if (nt < 15)
                STAGE(Bg + (size_t)(nt + 1) * 128 * DD, (i + 1) & 1)

#pragma unroll
            for (int ksl = 0; ksl < 2; ++ksl) {
                f16x8 bf[4];
#pragma unroll
                for (int ni = 0; ni < 4; ++ni) {
                    const int row = wn * 64 + ni * 16 + l15;
                    const int pos = (ksl * 4 + quad) ^ (row & 7);
                    bf[ni] = *(const f16x8*)((const char*)Buf[i & 1] + row * 128 + pos * 16);
                }
#pragma unroll
                for (int mi = 0; mi < 4; ++mi)
#pragma unroll
                    for (int ni = 0; ni < 4; ++ni)
                        acc[mi][ni] = __builtin_amdgcn_mfma_f32_16x16x32_f16(
                            af[mi][kc * 2 + ksl], bf[ni], acc[mi][ni], 0, 0, 0);
            }
        }
        // fold this query tile's contribution into the running row max
#pragma unroll
        for (int mi = 0; mi < 4; ++mi)
#pragma unroll
            for (int r = 0; r < 4; ++r)
                rm[mi][r] = fmaxf(rm[mi][r],
                                  fmaxf(fmaxf(acc[mi][0][r], acc[mi][1][r]),
                                        fmaxf(acc[mi][2][r], acc[mi][3][r])));
    }

    // ---- epilogue: reduce over the 16 col lanes, then the two wn halves
#pragma unroll
    for (int sh = 1; sh <= 8; sh <<= 1)
#pragma unroll
        for (int mi = 0; mi < 4; ++mi)
#pragma unroll
            for (int r = 0; r < 4; ++r)
                rm[mi][r] = fmaxf(rm[mi][r], __shfl_xor(rm[mi][r], sh, 64));

    if (l15 == 0) {
#pragma unroll
        for (int mi = 0; mi < 4; ++mi)
#pragma unroll
            for (int r = 0; r < 4; ++r)
                red[wn][wm * 64 + mi * 16 + quad * 4 + r] = rm[mi][r];
    }
    __syncthreads();
    if (tid < 128)
        scores[(size_t)b * LC + mt * 128 + tid] = fmaxf(red[0][tid], red[1][tid]);
    #undef STAGE
}

// Per batch: softmax over the 4096 final scores.
__global__ __launch_bounds__(256)
void stats_kernel(const float* __restrict__ scores, float* __restrict__ probs) {
    const int b    = blockIdx.x;
    const int tid  = threadIdx.x;
    const int lane = tid & 63;
    const int wave = tid >> 6;
    __shared__ float smax[4];
    __shared__ float ssum[4];

    float sv[16];
    float lmax = -3.4e38f;
#pragma unroll
    for (int j = 0; j < 16; ++j) {
        sv[j] = scores[(size_t)b * LC + tid + j * 256];
        lmax  = fmaxf(lmax, sv[j]);
    }
    for (int sh = 1; sh < 64; sh <<= 1)
        lmax = fmaxf(lmax, __shfl_xor(lmax, sh, 64));
    if (lane == 0) smax[wave] = lmax;
    __syncthreads();
    const float M = fmaxf(fmaxf(smax[0], smax[1]), fmaxf(smax[2], smax[3]));

    float lsum = 0.f;
#pragma unroll
    for (int j = 0; j < 16; ++j) {
        sv[j] = expf(sv[j] - M);
        lsum += sv[j];
    }
    for (int sh = 1; sh < 64; sh <<= 1)
        lsum += __shfl_xor(lsum, sh, 64);
    if (lane == 0) ssum[wave] = lsum;
    __syncthreads();
    const float inv = 1.f / (ssum[0] + ssum[1] + ssum[2] + ssum[3]);
#pragma unroll
    for (int j = 0; j < 16; ++j)
        probs[(size_t)b * LC + tid + j * 256] = sv[j] * inv;
}

// out[b][d] = sum_c probs[b][c] * ctx_f16[b][c][d]; 64 chunks/batch + atomicAdd.
__global__ __launch_bounds__(256)
void out_kernel(const float* __restrict__ probs, const _Float16* __restrict__ cf,
                float* __restrict__ out) {
    const int ch = blockIdx.x;   // 0..63
    const int b  = blockIdx.y;   // 0..7
    const int d  = threadIdx.x;  // 0..255
    const _Float16* cb = cf + (((size_t)b * LC) + (size_t)ch * 64) * DD;
    const float* pb = probs + (size_t)b * LC + ch * 64;
    float acc = 0.f;
#pragma unroll 16
    for (int i = 0; i < 64; ++i)
        acc += pb[i] * (float)cb[(size_t)i * DD + d];
    atomicAdd(&out[b * DD + d], acc);
}

extern "C" void kernel_launch(void* const* d_in, const int* in_sizes, int n_in,
                              void* d_out, int out_size, void* d_ws, size_t ws_size,
                              hipStream_t stream) {
    const float* q   = (const float*)d_in[0];   // [8, 2048, 256] f32
    const float* ctx = (const float*)d_in[1];   // [8, 4096, 256] f32
    float* out = (float*)d_out;                 // [8, 1, 256] f32

    // ws layout (bytes):
    //   qf     @ 0         : 8*2048*256*2  =  8,388,608
    //   cf     @ 8388608   : 8*4096*256*2  = 16,777,216
    //   scores @ 25165824  : 8*4096*4      =    131,072
    //   probs  @ 25296896  : 8*4096*4      =    131,072
    char* ws = (char*)d_ws;
    _Float16* qf  = (_Float16*)(ws);
    _Float16* cf  = (_Float16*)(ws + 8388608);
    float* scores = (float*)(ws + 25165824);
    float* probs  = (float*)(ws + 25296896);

    hipMemsetAsync(d_out, 0, (size_t)out_size * sizeof(float), stream);
    convert_all<<<12288, 256, 0, stream>>>(q, ctx, qf, cf);
    gemm_max_kernel<<<dim3(32, 8), 256, 0, stream>>>(qf, cf, scores);
    stats_kernel<<<8, 256, 0, stream>>>(scores, probs);
    out_kernel<<<dim3(64, 8), 256, 0, stream>>>(probs, cf, out);
}